// Round 1
// baseline (8529.552 us; speedup 1.0000x reference)
//
#include <hip/hip_runtime.h>
#include <math.h>

#define TT 1024
#define DD 512

typedef unsigned int u32;
typedef unsigned long long u64;
typedef _Float16 half2_t __attribute__((ext_vector_type(2)));

// ---------------- tagged cross-block atomics (agent scope, relaxed; R2-proven) ----
static __device__ __forceinline__ u64 aload64(const u64* p) {
    return __hip_atomic_load(p, __ATOMIC_RELAXED, __HIP_MEMORY_SCOPE_AGENT);
}
static __device__ __forceinline__ void astore64(u64* p, u64 v) {
    __hip_atomic_store(p, v, __ATOMIC_RELAXED, __HIP_MEMORY_SCOPE_AGENT);
}
static __device__ __forceinline__ u32 pkh2(float lo, float hi) {
    return __builtin_bit_cast(u32, __builtin_amdgcn_cvt_pkrtz(lo, hi));
}
static __device__ __forceinline__ float2 uph2(u32 v) {
    half2_t h = __builtin_bit_cast(half2_t, v);
    return make_float2((float)h.x, (float)h.y);
}
static __device__ __forceinline__ u64 mkword(u32 pay, u32 tag) {
    return ((u64)tag << 32) | (u64)pay;
}

static __device__ __forceinline__ float redux8(float v) {
    v += __shfl_xor(v, 1); v += __shfl_xor(v, 2); v += __shfl_xor(v, 4); return v;
}
static __device__ __forceinline__ float sum64(float v) {
    #pragma unroll
    for (int o = 32; o > 0; o >>= 1) v += __shfl_xor(v, o);
    return v;
}
static __device__ __forceinline__ float expc(float x) { return __expf(fminf(x, 60.f)); }
static __device__ __forceinline__ float fast_tanh(float x) {
    float xc = fminf(fmaxf(x, -15.f), 15.f);
    float e = __expf(2.f * xc);
    return (e - 1.f) / (e + 1.f);
}

// ---------------- projection GEMM (unchanged) ----------------
__global__ __launch_bounds__(256) void proj_kernel(const float* __restrict__ x,
                                                   const float* __restrict__ Wxz,
                                                   float* __restrict__ xp,
                                                   float* __restrict__ z) {
    __shared__ float As[16][66];
    __shared__ float Bs[16][66];
    const int m0 = blockIdx.x * 64;
    const int n0 = blockIdx.y * 64;
    const int tid = threadIdx.x;
    const int tm = tid / 16, tn = tid % 16;
    float c[4][4] = {};
    for (int k0 = 0; k0 < 512; k0 += 16) {
        const int r = tid >> 2, c4 = (tid & 3) * 4;
        float4 a4 = *(const float4*)(x + (size_t)(m0 + r) * 512 + k0 + c4);
        float4 b4 = *(const float4*)(Wxz + (size_t)(n0 + r) * 512 + k0 + c4);
        As[c4 + 0][r] = a4.x; As[c4 + 1][r] = a4.y; As[c4 + 2][r] = a4.z; As[c4 + 3][r] = a4.w;
        Bs[c4 + 0][r] = b4.x; Bs[c4 + 1][r] = b4.y; Bs[c4 + 2][r] = b4.z; Bs[c4 + 3][r] = b4.w;
        __syncthreads();
        #pragma unroll
        for (int k = 0; k < 16; ++k) {
            float a0 = As[k][tm * 4 + 0], a1 = As[k][tm * 4 + 1];
            float a2 = As[k][tm * 4 + 2], a3 = As[k][tm * 4 + 3];
            float b0 = Bs[k][tn * 4 + 0], b1 = Bs[k][tn * 4 + 1];
            float b2 = Bs[k][tn * 4 + 2], b3 = Bs[k][tn * 4 + 3];
            c[0][0] += a0 * b0; c[0][1] += a0 * b1; c[0][2] += a0 * b2; c[0][3] += a0 * b3;
            c[1][0] += a1 * b0; c[1][1] += a1 * b1; c[1][2] += a1 * b2; c[1][3] += a1 * b3;
            c[2][0] += a2 * b0; c[2][1] += a2 * b1; c[2][2] += a2 * b2; c[2][3] += a2 * b3;
            c[3][0] += a3 * b0; c[3][1] += a3 * b1; c[3][2] += a3 * b2; c[3][3] += a3 * b3;
        }
        __syncthreads();
    }
    #pragma unroll
    for (int i = 0; i < 4; ++i) {
        const int m = m0 + tm * 4 + i;
        #pragma unroll
        for (int j = 0; j < 4; ++j) {
            const int e = n0 + tn * 4 + j;
            if (e < 512) xp[(size_t)m * 512 + e] = c[i][j];
            else         z[(size_t)m * 512 + (e - 512)] = c[i][j];
        }
    }
}

// ---------------- recurrence: 64 blocks = 8 batches x 8 d-chunks ----------------
// SINGLE-HOP design: every block holds a FULL fp32 replica of its batch's tape
// (64x512, XOR-swizzled columns, 128 KB LDS). Per step only ONE cross-block
// exchange (h chunk + full-D W_write contribution, both fp16-packed as before).
// Both softmaxes + tape lerp are computed locally and bitwise-identically in all
// 8 blocks of a batch (identical fp16 inputs, identical op order), so replicas
// never diverge. The hop's LLC round-trip hides under the 128KB lerp pass, with
// poll loads pre-issued midway through it. W_h . h(t) for step t+1 is folded
// into the post-gather dot pass (reuses the h fragments -> no extra LDS reads).
__global__ __launch_bounds__(512) void rec_kernel(
    const float* __restrict__ tape0, const float* __restrict__ hwork0,
    const float* __restrict__ W_h, const float* __restrict__ b_h,
    const float* __restrict__ W_write,
    const float* __restrict__ g_z, const float* __restrict__ g_r,
    const float* __restrict__ g_h, const float* __restrict__ b_gate,
    const float* __restrict__ Zbuf,
    float* __restrict__ out, float* __restrict__ tape_out,
    u64* hA, u64* cA) {
    // full tape replica, column-swizzled: element (n,c) at tp[n][c ^ ((n&7)<<2)]
    __shared__ __align__(16) float tp[64][512];      // 128 KB
    __shared__ __align__(16) float hw2[8][68];       // full h(t), pitch 68 (conflict-free f4)
    __shared__ __align__(16) float wvp[8][68];       // full wv(t), pitch 68
    __shared__ float red[8][64];                     // rv partial per wave
    __shared__ __align__(16) float hnc[64];
    __shared__ float rvc[64], xpc[64], zc[64];
    __shared__ float a_l[64], c1_l[64], hhc[64], ws_l[64], q0_l[64];
    __shared__ float c2_s;

    const int b = blockIdx.x & 7, s = blockIdx.x >> 3;   // batch -> XCD, chunk
    const int tid = threadIdx.x, lane = tid & 63, wid = tid >> 6;
    const int nrow = tid >> 3, l = tid & 7;              // (tape row, 64-col slice)
    const int sw = (nrow & 7) << 2;                      // per-row column XOR (dwords)
    const int d0 = s * 64;
    const float scale = 0.044194173824159216f;           // 1/sqrt(512)

    // --- resident weights (128 VGPRs) ---
    float4 wh[16];    // W_h[d0+nrow][l*64 + 4j..]  (dot-slice layout == (nrow,l))
    float4 wwc[16];   // W_write[tid][d0 + 4j..]
    {
        const float4* w1 = (const float4*)(W_h + (size_t)(d0 + nrow) * DD + l * 64);
        #pragma unroll
        for (int j = 0; j < 16; ++j) wh[j] = w1[j];
        const float4* w2 = (const float4*)(W_write + (size_t)tid * DD + d0);
        #pragma unroll
        for (int j = 0; j < 16; ++j) wwc[j] = w2[j];
    }
    float bhr = 0.f, gz = 0.f, gr = 0.f, gh = 0.f, bg = 0.f;
    if (wid == 0) bhr = b_h[d0 + lane];
    if (wid == 1) { gz = g_z[d0 + lane]; gr = g_r[d0 + lane]; gh = g_h[d0 + lane]; bg = b_gate[d0 + lane]; }

    // --- init LDS: full tape (swizzled), h(-1), zeros ---
    {
        const float* src = tape0 + (size_t)(b * 64 + nrow) * DD;
        #pragma unroll
        for (int i = 0; i < 16; ++i) {
            float4 v = *(const float4*)(src + l * 64 + 4 * i);
            *(float4*)&tp[nrow][(l * 64 + 4 * i) ^ sw] = v;
        }
    }
    hw2[tid >> 6][tid & 63] = hwork0[(size_t)b * DD + tid];
    {
        float* pw = &wvp[0][0];
        for (int i = tid; i < 8 * 68; i += 512) pw[i] = 0.f;
    }
    if (tid < 64) a_l[tid] = 0.f;
    if (tid == 0) c2_s = 0.f;
    // prefetch xp/z for t=0
    float xpr = 0.f, zr = 0.f;
    if (wid == 2)      xpr = out[((size_t)(b * TT)) * DD + d0 + lane];
    else if (wid == 3) zr  = Zbuf[((size_t)(b * TT)) * DD + d0 + lane];
    __syncthreads();

    // --- bootstrap (fully local, no hop): q0(n)=h(-1).tape, hh=W_h.h(-1) ---
    {
        float q0 = 0.f, hh = 0.f;
        #pragma unroll
        for (int i = 0; i < 16; ++i) {
            float4 t4 = *(const float4*)&tp[nrow][(l * 64 + 4 * i) ^ sw];
            float4 h4 = *(const float4*)&hw2[l][4 * i];
            q0 += t4.x * h4.x + t4.y * h4.y + t4.z * h4.z + t4.w * h4.w;
            hh += wh[i].x * h4.x + wh[i].y * h4.y + wh[i].z * h4.z + wh[i].w * h4.w;
        }
        q0 = redux8(q0); hh = redux8(hh);
        if (l == 0) { q0_l[nrow] = q0; hhc[nrow] = hh; }
    }
    __syncthreads();
    if (wid == 0) {
        float er = expc(scale * q0_l[lane]);
        float Zr = sum64(er);
        c1_l[lane] = __fdividef(er, Zr);   // c1 = r(0) (a(-1)=0 -> c2=0)
    }
    __syncthreads();

    // ---------------- main scan ----------------
    for (int t = 0; t < TT; ++t) {
        const int p = t & 1;
        const u32 tg = (u32)(t + 1);

        // ---- A: rv partials over pre-lerp tape (c1/c2 trick); stage xp/z ----
        if (wid == 2)      xpc[lane] = xpr;
        else if (wid == 3) zc[lane] = zr;
        {
            float acc = 0.f;
            #pragma unroll
            for (int k = 0; k < 8; ++k)
                acc += c1_l[wid * 8 + k] * tp[wid * 8 + k][(d0 + lane) ^ (k << 2)];
            red[wid][lane] = acc;
        }
        __syncthreads();                                   // B1
        // ---- B: h(t) chunk (wave0) ----
        if (wid == 0) {
            float rv = c2_s * wvp[s][lane];
            #pragma unroll
            for (int w = 0; w < 8; ++w) rv += red[w][lane];
            rvc[lane] = rv;
            hnc[lane] = fast_tanh(xpc[lane] + hhc[lane] + rv + bhr);
        }
        __syncthreads();                                   // B2
        // ---- C: publish h chunk + full-D c contribution; out(t) epilogue ----
        if (wid == 0 && !(lane & 1))
            astore64(&hA[((size_t)p * 8 + b) * 256 + s * 32 + (lane >> 1)],
                     mkword(pkh2(hnc[lane], hnc[lane + 1]), tg));
        {
            float cj = 0.f;
            #pragma unroll
            for (int j = 0; j < 16; ++j) {
                float4 h4 = *(const float4*)&hnc[4 * j];
                cj += wwc[j].x * h4.x + wwc[j].y * h4.y + wwc[j].z * h4.z + wwc[j].w * h4.w;
            }
            float cn = __shfl_xor(cj, 1);
            if (!(tid & 1))
                astore64(&cA[(((size_t)p * 8 + b) * 8 + s) * 256 + (tid >> 1)],
                         mkword(pkh2(cj, cn), tg));
        }
        if (wid == 1) {
            float h = hnc[lane];
            float g = zc[lane] * gz + rvc[lane] * gr + h * gh + bg;
            g = fminf(fmaxf(g, -20.f), 20.f);
            float sig = 1.f / (1.f + __expf(-g));
            out[((size_t)(b * TT + t)) * DD + d0 + lane] = h * g * sig;
        }
        // ---- D: full-tape lerp a(t-1),wv(t-1) (hop shadow); poll pre-issue midway ----
        const float an = a_l[nrow];
        #pragma unroll
        for (int i = 0; i < 8; ++i) {
            const int c = (l * 64 + 4 * i) ^ sw;
            float4 t4 = *(const float4*)&tp[nrow][c];
            float4 w4 = *(const float4*)&wvp[l][4 * i];
            t4.x += an * (w4.x - t4.x); t4.y += an * (w4.y - t4.y);
            t4.z += an * (w4.z - t4.z); t4.w += an * (w4.w - t4.w);
            *(float4*)&tp[nrow][c] = t4;
        }
        u64 v0 = 0, v1 = 0, v2 = 0, v3 = 0, v4 = 0, v5 = 0, v6 = 0, v7 = 0, vhw = 0;
        if (tid < 256) {
            const u64* cb = cA + (((size_t)p * 8 + b) * 8) * 256 + tid;
            v0 = aload64(cb + 0 * 256); v1 = aload64(cb + 1 * 256);
            v2 = aload64(cb + 2 * 256); v3 = aload64(cb + 3 * 256);
            v4 = aload64(cb + 4 * 256); v5 = aload64(cb + 5 * 256);
            v6 = aload64(cb + 6 * 256); v7 = aload64(cb + 7 * 256);
        } else {
            vhw = aload64(hA + ((size_t)p * 8 + b) * 256 + (tid - 256));
        }
        #pragma unroll
        for (int i = 8; i < 16; ++i) {
            const int c = (l * 64 + 4 * i) ^ sw;
            float4 t4 = *(const float4*)&tp[nrow][c];
            float4 w4 = *(const float4*)&wvp[l][4 * i];
            t4.x += an * (w4.x - t4.x); t4.y += an * (w4.y - t4.y);
            t4.z += an * (w4.z - t4.z); t4.w += an * (w4.w - t4.w);
            *(float4*)&tp[nrow][c] = t4;
        }
        __syncthreads();                                   // B3
        // ---- E: tag-check / gather: wv(t) full (sum of 8 contribs) + h(t) full ----
        if (tid < 256) {
            const u64* cb = cA + (((size_t)p * 8 + b) * 8) * 256 + tid;
            for (;;) {
                u32 m = 0;
                if ((u32)(v0 >> 32) == tg) m |= 1u;   if ((u32)(v1 >> 32) == tg) m |= 2u;
                if ((u32)(v2 >> 32) == tg) m |= 4u;   if ((u32)(v3 >> 32) == tg) m |= 8u;
                if ((u32)(v4 >> 32) == tg) m |= 16u;  if ((u32)(v5 >> 32) == tg) m |= 32u;
                if ((u32)(v6 >> 32) == tg) m |= 64u;  if ((u32)(v7 >> 32) == tg) m |= 128u;
                if (m == 0xffu) break;
                __builtin_amdgcn_s_sleep(1);
                if (!(m & 1u))   v0 = aload64(cb + 0 * 256);
                if (!(m & 2u))   v1 = aload64(cb + 1 * 256);
                if (!(m & 4u))   v2 = aload64(cb + 2 * 256);
                if (!(m & 8u))   v3 = aload64(cb + 3 * 256);
                if (!(m & 16u))  v4 = aload64(cb + 4 * 256);
                if (!(m & 32u))  v5 = aload64(cb + 5 * 256);
                if (!(m & 64u))  v6 = aload64(cb + 6 * 256);
                if (!(m & 128u)) v7 = aload64(cb + 7 * 256);
            }
            float lo = 0.f, hi = 0.f; float2 f;
            f = uph2((u32)v0); lo += f.x; hi += f.y;
            f = uph2((u32)v1); lo += f.x; hi += f.y;
            f = uph2((u32)v2); lo += f.x; hi += f.y;
            f = uph2((u32)v3); lo += f.x; hi += f.y;
            f = uph2((u32)v4); lo += f.x; hi += f.y;
            f = uph2((u32)v5); lo += f.x; hi += f.y;
            f = uph2((u32)v6); lo += f.x; hi += f.y;
            f = uph2((u32)v7); lo += f.x; hi += f.y;
            wvp[tid >> 5][2 * (tid & 31)]     = lo;
            wvp[tid >> 5][2 * (tid & 31) + 1] = hi;
        } else {
            const int k = tid - 256;
            const u64* hb = hA + ((size_t)p * 8 + b) * 256 + k;
            for (;;) {
                if ((u32)(vhw >> 32) == tg) break;
                __builtin_amdgcn_s_sleep(1);
                vhw = aload64(hb);
            }
            float2 hp = uph2((u32)vhw);
            hw2[k >> 5][2 * (k & 31)]     = hp.x;
            hw2[k >> 5][2 * (k & 31) + 1] = hp.y;
        }
        __syncthreads();                                   // B4
        // ---- F: local dots ws/q0 vs tape(t-1) + NEXT-step hh (folded) + hwv; prefetch ----
        float hwv = 0.f;
        {
            float ws = 0.f, q0 = 0.f, hh = 0.f;
            #pragma unroll
            for (int i = 0; i < 16; ++i) {
                float4 t4 = *(const float4*)&tp[nrow][(l * 64 + 4 * i) ^ sw];
                float4 w4 = *(const float4*)&wvp[l][4 * i];
                float4 h4 = *(const float4*)&hw2[l][4 * i];
                ws += w4.x * t4.x + w4.y * t4.y + w4.z * t4.z + w4.w * t4.w;
                q0 += h4.x * t4.x + h4.y * t4.y + h4.z * t4.z + h4.w * t4.w;
                hh += wh[i].x * h4.x + wh[i].y * h4.y + wh[i].z * h4.z + wh[i].w * h4.w;
            }
            ws = redux8(ws); q0 = redux8(q0); hh = redux8(hh);
            if (l == 0) { ws_l[nrow] = ws; q0_l[nrow] = q0; hhc[nrow] = hh; }
        }
        if (wid == 0) {   // hwv = h(t).wv(t), kept in register for G
            const int r8 = lane >> 3, c8 = (lane & 7) * 8;
            float a = 0.f;
            #pragma unroll
            for (int k = 0; k < 8; ++k) a += hw2[r8][c8 + k] * wvp[r8][c8 + k];
            hwv = sum64(a);
        }
        if (wid == 2 && t + 1 < TT)      xpr = out[((size_t)(b * TT + t + 1)) * DD + d0 + lane];
        else if (wid == 3 && t + 1 < TT) zr  = Zbuf[((size_t)(b * TT + t + 1)) * DD + d0 + lane];
        __syncthreads();                                   // B5
        // ---- G: both softmaxes locally (wave0), fused next-read-score ----
        if (wid == 0) {
            float ew = expc(scale * ws_l[lane]);
            float Zw = sum64(ew);
            float a = __fdividef(ew, Zw);
            float q = (1.f - a) * q0_l[lane] + a * hwv;
            float er = expc(scale * q);
            float Zr = sum64(er);
            float r = __fdividef(er, Zr);
            a_l[lane] = a;
            c1_l[lane] = r * (1.f - a);
            float c2 = sum64(r * a);
            if (lane == 0) c2_s = c2;
        }
        __syncthreads();                                   // B6
    }

    // ---- epilogue: final lerp (a(T-1), wv(T-1)) + write own chunk ----
    {
        const float an = a_l[nrow];
        float* dst = tape_out + ((size_t)(b * 64 + nrow)) * DD;
        #pragma unroll
        for (int i = 0; i < 2; ++i) {
            const int c0 = d0 + l * 8 + 4 * i;
            float4 t4 = *(const float4*)&tp[nrow][c0 ^ sw];
            float4 w4 = *(const float4*)&wvp[s][l * 8 + 4 * i];
            t4.x += an * (w4.x - t4.x); t4.y += an * (w4.y - t4.y);
            t4.z += an * (w4.z - t4.z); t4.w += an * (w4.w - t4.w);
            *(float4*)(dst + c0) = t4;
        }
    }
}

extern "C" void kernel_launch(void* const* d_in, const int* in_sizes, int n_in,
                              void* d_out, int out_size, void* d_ws, size_t ws_size,
                              hipStream_t stream) {
    const float* x       = (const float*)d_in[0];   // [8,1024,512]
    const float* tape0   = (const float*)d_in[1];   // [8,64,512]
    const float* hwork0  = (const float*)d_in[2];   // [8,512]
    const float* W_h     = (const float*)d_in[3];   // [512,512]
    const float* W_xz    = (const float*)d_in[4];   // [1024,512]
    const float* b_h     = (const float*)d_in[5];   // [512]
    const float* W_write = (const float*)d_in[6];   // [512,512]
    const float* g_z     = (const float*)d_in[7];
    const float* g_r     = (const float*)d_in[8];
    const float* g_h     = (const float*)d_in[9];
    const float* b_gate  = (const float*)d_in[10];

    float* out  = (float*)d_out;                        // outs [8,1024,512]
    float* tout = out + (size_t)8 * TT * DD;            // tape_final [8,64,512]

    char* ws = (char*)d_ws;
    u64* hA   = (u64*)ws;                               // [2][8][256]      = 32 KB
    u64* cA   = (u64*)(ws + 32768);                     // [2][8][8][256]   = 256 KB
    float* Zbuf = (float*)(ws + 393216);                // 16 MB

    (void)in_sizes; (void)n_in; (void)out_size; (void)ws_size;

    // tags equality-checked against monotone values; 0xAA poison never matches.
    dim3 pgrid(128, 16);
    proj_kernel<<<pgrid, 256, 0, stream>>>(x, W_xz, out, Zbuf);
    rec_kernel<<<64, 512, 0, stream>>>(tape0, hwork0, W_h, b_h, W_write,
                                       g_z, g_r, g_h, b_gate, Zbuf,
                                       out, tout, hA, cA);
}

// Round 2
// 4977.394 us; speedup vs baseline: 1.7137x; 1.7137x over previous
//
#include <hip/hip_runtime.h>
#include <math.h>

#define TT 1024
#define DD 512

typedef unsigned int u32;
typedef unsigned long long u64;
typedef _Float16 half2_t __attribute__((ext_vector_type(2)));

// ---------------- tagged cross-block atomics (agent scope, relaxed; R2-proven) ----
static __device__ __forceinline__ u64 aload64(const u64* p) {
    return __hip_atomic_load(p, __ATOMIC_RELAXED, __HIP_MEMORY_SCOPE_AGENT);
}
static __device__ __forceinline__ void astore64(u64* p, u64 v) {
    __hip_atomic_store(p, v, __ATOMIC_RELAXED, __HIP_MEMORY_SCOPE_AGENT);
}
static __device__ __forceinline__ u32 pkh2(float lo, float hi) {
    return __builtin_bit_cast(u32, __builtin_amdgcn_cvt_pkrtz(lo, hi));
}
static __device__ __forceinline__ float2 uph2(u32 v) {
    half2_t h = __builtin_bit_cast(half2_t, v);
    return make_float2((float)h.x, (float)h.y);
}
static __device__ __forceinline__ u64 mkword(u32 pay, u32 tag) {
    return ((u64)tag << 32) | (u64)pay;
}

static __device__ __forceinline__ float redux8(float v) {
    v += __shfl_xor(v, 1); v += __shfl_xor(v, 2); v += __shfl_xor(v, 4); return v;
}
static __device__ __forceinline__ float sum64(float v) {
    #pragma unroll
    for (int o = 32; o > 0; o >>= 1) v += __shfl_xor(v, o);
    return v;
}
static __device__ __forceinline__ float expc(float x) { return __expf(fminf(x, 60.f)); }
static __device__ __forceinline__ float fast_tanh(float x) {
    float xc = fminf(fmaxf(x, -15.f), 15.f);
    float e = __expf(2.f * xc);
    return (e - 1.f) / (e + 1.f);
}

// ---------------- projection GEMM (unchanged) ----------------
__global__ __launch_bounds__(256) void proj_kernel(const float* __restrict__ x,
                                                   const float* __restrict__ Wxz,
                                                   float* __restrict__ xp,
                                                   float* __restrict__ z) {
    __shared__ float As[16][66];
    __shared__ float Bs[16][66];
    const int m0 = blockIdx.x * 64;
    const int n0 = blockIdx.y * 64;
    const int tid = threadIdx.x;
    const int tm = tid / 16, tn = tid % 16;
    float c[4][4] = {};
    for (int k0 = 0; k0 < 512; k0 += 16) {
        const int r = tid >> 2, c4 = (tid & 3) * 4;
        float4 a4 = *(const float4*)(x + (size_t)(m0 + r) * 512 + k0 + c4);
        float4 b4 = *(const float4*)(Wxz + (size_t)(n0 + r) * 512 + k0 + c4);
        As[c4 + 0][r] = a4.x; As[c4 + 1][r] = a4.y; As[c4 + 2][r] = a4.z; As[c4 + 3][r] = a4.w;
        Bs[c4 + 0][r] = b4.x; Bs[c4 + 1][r] = b4.y; Bs[c4 + 2][r] = b4.z; Bs[c4 + 3][r] = b4.w;
        __syncthreads();
        #pragma unroll
        for (int k = 0; k < 16; ++k) {
            float a0 = As[k][tm * 4 + 0], a1 = As[k][tm * 4 + 1];
            float a2 = As[k][tm * 4 + 2], a3 = As[k][tm * 4 + 3];
            float b0 = Bs[k][tn * 4 + 0], b1 = Bs[k][tn * 4 + 1];
            float b2 = Bs[k][tn * 4 + 2], b3 = Bs[k][tn * 4 + 3];
            c[0][0] += a0 * b0; c[0][1] += a0 * b1; c[0][2] += a0 * b2; c[0][3] += a0 * b3;
            c[1][0] += a1 * b0; c[1][1] += a1 * b1; c[1][2] += a1 * b2; c[1][3] += a1 * b3;
            c[2][0] += a2 * b0; c[2][1] += a2 * b1; c[2][2] += a2 * b2; c[2][3] += a2 * b3;
            c[3][0] += a3 * b0; c[3][1] += a3 * b1; c[3][2] += a3 * b2; c[3][3] += a3 * b3;
        }
        __syncthreads();
    }
    #pragma unroll
    for (int i = 0; i < 4; ++i) {
        const int m = m0 + tm * 4 + i;
        #pragma unroll
        for (int j = 0; j < 4; ++j) {
            const int e = n0 + tn * 4 + j;
            if (e < 512) xp[(size_t)m * 512 + e] = c[i][j];
            else         z[(size_t)m * 512 + (e - 512)] = c[i][j];
        }
    }
}

// ---------------- recurrence: 64 blocks = 8 batches x 8 d-chunks ----------------
// SINGLE-HOP design with FIXED swizzle. Every block holds a FULL fp32 replica of
// its batch's tape (64x512) in LDS. Swizzle: logical (n,c) stored at column
//   c ^ ((((c>>6) ^ n) & 7) << 2)
// so that in the b128 passes (thread nrow=tid>>3, l=tid&7 owning cols l*64..),
// the bank-quad is 4*((i ^ l ^ nrow)&7): consecutive-8 lanes hit 8 DISTINCT
// quads (the m134 conflict-free structure). Old swizzle had quad independent of
// l -> 8-way conflict on every tape op (672M conflict cycles).
__global__ __launch_bounds__(512) void rec_kernel(
    const float* __restrict__ tape0, const float* __restrict__ hwork0,
    const float* __restrict__ W_h, const float* __restrict__ b_h,
    const float* __restrict__ W_write,
    const float* __restrict__ g_z, const float* __restrict__ g_r,
    const float* __restrict__ g_h, const float* __restrict__ b_gate,
    const float* __restrict__ Zbuf,
    float* __restrict__ out, float* __restrict__ tape_out,
    u64* hA, u64* cA) {
    __shared__ __align__(16) float tp[64][512];      // 128 KB tape replica (swizzled)
    __shared__ __align__(16) float hw2[8][68];       // full h(t), pitch 68
    __shared__ __align__(16) float wvp[8][68];       // full wv(t), pitch 68
    __shared__ float red[8][64];                     // rv partial per wave
    __shared__ __align__(16) float hnc[64];
    __shared__ float rvc[64], xpc[64], zc[64];
    __shared__ float a_l[64], c1_l[64], hhc[64], ws_l[64], q0_l[64];
    __shared__ float c2_s;

    const int b = blockIdx.x & 7, s = blockIdx.x >> 3;   // batch -> XCD, chunk
    const int tid = threadIdx.x, lane = tid & 63, wid = tid >> 6;
    const int nrow = tid >> 3, l = tid & 7;              // (tape row, 64-col slice)
    const int sw = ((l ^ nrow) & 7) << 2;                // per-thread col XOR (dwords)
    const int d0 = s * 64;
    const float scale = 0.044194173824159216f;           // 1/sqrt(512)

    // --- resident weights (128 VGPRs) ---
    float4 wh[16];    // W_h[d0+nrow][l*64 + 4j..]  (dot-slice layout == (nrow,l))
    float4 wwc[16];   // W_write[tid][d0 + 4j..]
    {
        const float4* w1 = (const float4*)(W_h + (size_t)(d0 + nrow) * DD + l * 64);
        #pragma unroll
        for (int j = 0; j < 16; ++j) wh[j] = w1[j];
        const float4* w2 = (const float4*)(W_write + (size_t)tid * DD + d0);
        #pragma unroll
        for (int j = 0; j < 16; ++j) wwc[j] = w2[j];
    }
    float bhr = 0.f, gz = 0.f, gr = 0.f, gh = 0.f, bg = 0.f;
    if (wid == 0) bhr = b_h[d0 + lane];
    if (wid == 1) { gz = g_z[d0 + lane]; gr = g_r[d0 + lane]; gh = g_h[d0 + lane]; bg = b_gate[d0 + lane]; }

    // --- init LDS: full tape (swizzled), h(-1), zeros ---
    {
        const float* src = tape0 + (size_t)(b * 64 + nrow) * DD;
        #pragma unroll
        for (int i = 0; i < 16; ++i) {
            float4 v = *(const float4*)(src + l * 64 + 4 * i);
            *(float4*)&tp[nrow][(l * 64 + 4 * i) ^ sw] = v;
        }
    }
    hw2[tid >> 6][tid & 63] = hwork0[(size_t)b * DD + tid];
    {
        float* pw = &wvp[0][0];
        for (int i = tid; i < 8 * 68; i += 512) pw[i] = 0.f;
    }
    if (tid < 64) a_l[tid] = 0.f;
    if (tid == 0) c2_s = 0.f;
    // prefetch xp/z for t=0
    float xpr = 0.f, zr = 0.f;
    if (wid == 2)      xpr = out[((size_t)(b * TT)) * DD + d0 + lane];
    else if (wid == 3) zr  = Zbuf[((size_t)(b * TT)) * DD + d0 + lane];
    __syncthreads();

    // --- bootstrap (fully local, no hop): q0(n)=h(-1).tape, hh=W_h.h(-1) ---
    {
        float q0 = 0.f, hh = 0.f;
        #pragma unroll
        for (int i = 0; i < 16; ++i) {
            float4 t4 = *(const float4*)&tp[nrow][(l * 64 + 4 * i) ^ sw];
            float4 h4 = *(const float4*)&hw2[l][4 * i];
            q0 += t4.x * h4.x + t4.y * h4.y + t4.z * h4.z + t4.w * h4.w;
            hh += wh[i].x * h4.x + wh[i].y * h4.y + wh[i].z * h4.z + wh[i].w * h4.w;
        }
        q0 = redux8(q0); hh = redux8(hh);
        if (l == 0) { q0_l[nrow] = q0; hhc[nrow] = hh; }
    }
    __syncthreads();
    if (wid == 0) {
        float er = expc(scale * q0_l[lane]);
        float Zr = sum64(er);
        c1_l[lane] = __fdividef(er, Zr);   // c1 = r(0) (a(-1)=0 -> c2=0)
    }
    __syncthreads();

    // ---------------- main scan ----------------
    for (int t = 0; t < TT; ++t) {
        const int p = t & 1;
        const u32 tg = (u32)(t + 1);

        // ---- A: rv partials over pre-lerp tape (c1/c2 trick); stage xp/z ----
        if (wid == 2)      xpc[lane] = xpr;
        else if (wid == 3) zc[lane] = zr;
        {
            float acc = 0.f;
            #pragma unroll
            for (int k = 0; k < 8; ++k)
                acc += c1_l[wid * 8 + k] * tp[wid * 8 + k][(d0 + lane) ^ (((s ^ k) & 7) << 2)];
            red[wid][lane] = acc;
        }
        __syncthreads();                                   // B1
        // ---- B: h(t) chunk (wave0) ----
        if (wid == 0) {
            float rv = c2_s * wvp[s][lane];
            #pragma unroll
            for (int w = 0; w < 8; ++w) rv += red[w][lane];
            rvc[lane] = rv;
            hnc[lane] = fast_tanh(xpc[lane] + hhc[lane] + rv + bhr);
        }
        __syncthreads();                                   // B2
        // ---- C: publish h chunk + full-D c contribution; out(t) epilogue ----
        if (wid == 0 && !(lane & 1))
            astore64(&hA[((size_t)p * 8 + b) * 256 + s * 32 + (lane >> 1)],
                     mkword(pkh2(hnc[lane], hnc[lane + 1]), tg));
        {
            float cj = 0.f;
            #pragma unroll
            for (int j = 0; j < 16; ++j) {
                float4 h4 = *(const float4*)&hnc[4 * j];
                cj += wwc[j].x * h4.x + wwc[j].y * h4.y + wwc[j].z * h4.z + wwc[j].w * h4.w;
            }
            float cn = __shfl_xor(cj, 1);
            if (!(tid & 1))
                astore64(&cA[(((size_t)p * 8 + b) * 8 + s) * 256 + (tid >> 1)],
                         mkword(pkh2(cj, cn), tg));
        }
        if (wid == 1) {
            float h = hnc[lane];
            float g = zc[lane] * gz + rvc[lane] * gr + h * gh + bg;
            g = fminf(fmaxf(g, -20.f), 20.f);
            float sig = 1.f / (1.f + __expf(-g));
            out[((size_t)(b * TT + t)) * DD + d0 + lane] = h * g * sig;
        }
        // ---- D: full-tape lerp a(t-1),wv(t-1) (hop shadow); poll pre-issue midway ----
        const float an = a_l[nrow];
        #pragma unroll
        for (int i = 0; i < 8; ++i) {
            const int c = (l * 64 + 4 * i) ^ sw;
            float4 t4 = *(const float4*)&tp[nrow][c];
            float4 w4 = *(const float4*)&wvp[l][4 * i];
            t4.x += an * (w4.x - t4.x); t4.y += an * (w4.y - t4.y);
            t4.z += an * (w4.z - t4.z); t4.w += an * (w4.w - t4.w);
            *(float4*)&tp[nrow][c] = t4;
        }
        u64 v0 = 0, v1 = 0, v2 = 0, v3 = 0, v4 = 0, v5 = 0, v6 = 0, v7 = 0, vhw = 0;
        if (tid < 256) {
            const u64* cb = cA + (((size_t)p * 8 + b) * 8) * 256 + tid;
            v0 = aload64(cb + 0 * 256); v1 = aload64(cb + 1 * 256);
            v2 = aload64(cb + 2 * 256); v3 = aload64(cb + 3 * 256);
            v4 = aload64(cb + 4 * 256); v5 = aload64(cb + 5 * 256);
            v6 = aload64(cb + 6 * 256); v7 = aload64(cb + 7 * 256);
        } else {
            vhw = aload64(hA + ((size_t)p * 8 + b) * 256 + (tid - 256));
        }
        #pragma unroll
        for (int i = 8; i < 16; ++i) {
            const int c = (l * 64 + 4 * i) ^ sw;
            float4 t4 = *(const float4*)&tp[nrow][c];
            float4 w4 = *(const float4*)&wvp[l][4 * i];
            t4.x += an * (w4.x - t4.x); t4.y += an * (w4.y - t4.y);
            t4.z += an * (w4.z - t4.z); t4.w += an * (w4.w - t4.w);
            *(float4*)&tp[nrow][c] = t4;
        }
        __syncthreads();                                   // B3
        // ---- E: tag-check / gather: wv(t) full (sum of 8 contribs) + h(t) full ----
        if (tid < 256) {
            const u64* cb = cA + (((size_t)p * 8 + b) * 8) * 256 + tid;
            for (;;) {
                u32 m = 0;
                if ((u32)(v0 >> 32) == tg) m |= 1u;   if ((u32)(v1 >> 32) == tg) m |= 2u;
                if ((u32)(v2 >> 32) == tg) m |= 4u;   if ((u32)(v3 >> 32) == tg) m |= 8u;
                if ((u32)(v4 >> 32) == tg) m |= 16u;  if ((u32)(v5 >> 32) == tg) m |= 32u;
                if ((u32)(v6 >> 32) == tg) m |= 64u;  if ((u32)(v7 >> 32) == tg) m |= 128u;
                if (m == 0xffu) break;
                __builtin_amdgcn_s_sleep(1);
                if (!(m & 1u))   v0 = aload64(cb + 0 * 256);
                if (!(m & 2u))   v1 = aload64(cb + 1 * 256);
                if (!(m & 4u))   v2 = aload64(cb + 2 * 256);
                if (!(m & 8u))   v3 = aload64(cb + 3 * 256);
                if (!(m & 16u))  v4 = aload64(cb + 4 * 256);
                if (!(m & 32u))  v5 = aload64(cb + 5 * 256);
                if (!(m & 64u))  v6 = aload64(cb + 6 * 256);
                if (!(m & 128u)) v7 = aload64(cb + 7 * 256);
            }
            float lo = 0.f, hi = 0.f; float2 f;
            f = uph2((u32)v0); lo += f.x; hi += f.y;
            f = uph2((u32)v1); lo += f.x; hi += f.y;
            f = uph2((u32)v2); lo += f.x; hi += f.y;
            f = uph2((u32)v3); lo += f.x; hi += f.y;
            f = uph2((u32)v4); lo += f.x; hi += f.y;
            f = uph2((u32)v5); lo += f.x; hi += f.y;
            f = uph2((u32)v6); lo += f.x; hi += f.y;
            f = uph2((u32)v7); lo += f.x; hi += f.y;
            wvp[tid >> 5][2 * (tid & 31)]     = lo;
            wvp[tid >> 5][2 * (tid & 31) + 1] = hi;
        } else {
            const int k = tid - 256;
            const u64* hb = hA + ((size_t)p * 8 + b) * 256 + k;
            for (;;) {
                if ((u32)(vhw >> 32) == tg) break;
                __builtin_amdgcn_s_sleep(1);
                vhw = aload64(hb);
            }
            float2 hp = uph2((u32)vhw);
            hw2[k >> 5][2 * (k & 31)]     = hp.x;
            hw2[k >> 5][2 * (k & 31) + 1] = hp.y;
        }
        __syncthreads();                                   // B4
        // ---- F: local dots ws/q0 vs tape(t-1) + NEXT-step hh (folded) + hwv; prefetch ----
        float hwv = 0.f;
        {
            float ws = 0.f, q0 = 0.f, hh = 0.f;
            #pragma unroll
            for (int i = 0; i < 16; ++i) {
                float4 t4 = *(const float4*)&tp[nrow][(l * 64 + 4 * i) ^ sw];
                float4 w4 = *(const float4*)&wvp[l][4 * i];
                float4 h4 = *(const float4*)&hw2[l][4 * i];
                ws += w4.x * t4.x + w4.y * t4.y + w4.z * t4.z + w4.w * t4.w;
                q0 += h4.x * t4.x + h4.y * t4.y + h4.z * t4.z + h4.w * t4.w;
                hh += wh[i].x * h4.x + wh[i].y * h4.y + wh[i].z * h4.z + wh[i].w * h4.w;
            }
            ws = redux8(ws); q0 = redux8(q0); hh = redux8(hh);
            if (l == 0) { ws_l[nrow] = ws; q0_l[nrow] = q0; hhc[nrow] = hh; }
        }
        if (wid == 0) {   // hwv = h(t).wv(t), kept in register for G
            const int r8 = lane >> 3, c8 = (lane & 7) * 8;
            float a = 0.f;
            #pragma unroll
            for (int k = 0; k < 8; ++k) a += hw2[r8][c8 + k] * wvp[r8][c8 + k];
            hwv = sum64(a);
        }
        if (wid == 2 && t + 1 < TT)      xpr = out[((size_t)(b * TT + t + 1)) * DD + d0 + lane];
        else if (wid == 3 && t + 1 < TT) zr  = Zbuf[((size_t)(b * TT + t + 1)) * DD + d0 + lane];
        __syncthreads();                                   // B5
        // ---- G: both softmaxes locally (wave0), fused next-read-score ----
        if (wid == 0) {
            float ew = expc(scale * ws_l[lane]);
            float Zw = sum64(ew);
            float a = __fdividef(ew, Zw);
            float q = (1.f - a) * q0_l[lane] + a * hwv;
            float er = expc(scale * q);
            float Zr = sum64(er);
            float r = __fdividef(er, Zr);
            a_l[lane] = a;
            c1_l[lane] = r * (1.f - a);
            float c2 = sum64(r * a);
            if (lane == 0) c2_s = c2;
        }
        __syncthreads();                                   // B6
    }

    // ---- epilogue: final lerp (a(T-1), wv(T-1)) + write own chunk ----
    {
        const float an = a_l[nrow];
        const int esw = ((s ^ nrow) & 7) << 2;
        float* dst = tape_out + ((size_t)(b * 64 + nrow)) * DD;
        #pragma unroll
        for (int i = 0; i < 2; ++i) {
            const int c0 = d0 + l * 8 + 4 * i;
            float4 t4 = *(const float4*)&tp[nrow][c0 ^ esw];
            float4 w4 = *(const float4*)&wvp[s][l * 8 + 4 * i];
            t4.x += an * (w4.x - t4.x); t4.y += an * (w4.y - t4.y);
            t4.z += an * (w4.z - t4.z); t4.w += an * (w4.w - t4.w);
            *(float4*)(dst + c0) = t4;
        }
    }
}

extern "C" void kernel_launch(void* const* d_in, const int* in_sizes, int n_in,
                              void* d_out, int out_size, void* d_ws, size_t ws_size,
                              hipStream_t stream) {
    const float* x       = (const float*)d_in[0];   // [8,1024,512]
    const float* tape0   = (const float*)d_in[1];   // [8,64,512]
    const float* hwork0  = (const float*)d_in[2];   // [8,512]
    const float* W_h     = (const float*)d_in[3];   // [512,512]
    const float* W_xz    = (const float*)d_in[4];   // [1024,512]
    const float* b_h     = (const float*)d_in[5];   // [512]
    const float* W_write = (const float*)d_in[6];   // [512,512]
    const float* g_z     = (const float*)d_in[7];
    const float* g_r     = (const float*)d_in[8];
    const float* g_h     = (const float*)d_in[9];
    const float* b_gate  = (const float*)d_in[10];

    float* out  = (float*)d_out;                        // outs [8,1024,512]
    float* tout = out + (size_t)8 * TT * DD;            // tape_final [8,64,512]

    char* ws = (char*)d_ws;
    u64* hA   = (u64*)ws;                               // [2][8][256]      = 32 KB
    u64* cA   = (u64*)(ws + 32768);                     // [2][8][8][256]   = 256 KB
    float* Zbuf = (float*)(ws + 393216);                // 16 MB

    (void)in_sizes; (void)n_in; (void)out_size; (void)ws_size;

    // tags equality-checked against monotone values; 0xAA poison never matches.
    dim3 pgrid(128, 16);
    proj_kernel<<<pgrid, 256, 0, stream>>>(x, W_xz, out, Zbuf);
    rec_kernel<<<64, 512, 0, stream>>>(tape0, hwork0, W_h, b_h, W_write,
                                       g_z, g_r, g_h, b_gate, Zbuf,
                                       out, tout, hA, cA);
}